// Round 1
// baseline (1612.314 us; speedup 1.0000x reference)
//
#include <hip/hip_runtime.h>
#include <hip/hip_bf16.h>
#include <math.h>

#define FEAT 96
#define ACTF 32
#define HID 64

// ---------- helpers ----------
__device__ __forceinline__ unsigned fkey(float f) {
    unsigned u = __float_as_uint(f);
    return (u & 0x80000000u) ? ~u : (u | 0x80000000u);
}
__device__ __forceinline__ float funkey(unsigned k) {
    unsigned u = (k & 0x80000000u) ? (k ^ 0x80000000u) : ~k;
    return __uint_as_float(u);
}
__device__ __forceinline__ void atomAddF(float* p, float v) {
    __hip_atomic_fetch_add(p, v, __ATOMIC_RELAXED, __HIP_MEMORY_SCOPE_AGENT);
}
__device__ __forceinline__ float lrelu(float x) { return x >= 0.f ? x : 0.2f * x; }

// ---------- embedding: x0[N,64] = [nf|act] @ Wemb[128,64] + bemb ----------
__global__ void emb_kernel(const float* __restrict__ nf, const float* __restrict__ act,
                           const float* __restrict__ Wemb, const float* __restrict__ bemb,
                           float* __restrict__ x0, int N) {
    __shared__ float Wl[128 * 64];
    __shared__ float xl[4][128];
    for (int i = threadIdx.x; i < 128 * 64; i += 256) Wl[i] = Wemb[i];
    __syncthreads();
    int c = threadIdx.x & 63;
    int nl = threadIdx.x >> 6;
    for (long long base = (long long)blockIdx.x * 4; base < N; base += (long long)gridDim.x * 4) {
        for (int i = threadIdx.x; i < 4 * 128; i += 256) {
            long long node = base + (i >> 7);
            int k = i & 127;
            float v = 0.f;
            if (node < N) v = (k < FEAT) ? nf[node * FEAT + k] : act[node * ACTF + (k - FEAT)];
            xl[i >> 7][k] = v;
        }
        __syncthreads();
        long long node = base + nl;
        if (node < N) {
            float acc = bemb[c];
            #pragma unroll 8
            for (int k = 0; k < 128; ++k) acc += xl[nl][k] * Wl[k * 64 + c];
            x0[node * 64 + c] = acc;
        }
        __syncthreads();
    }
}

// ---------- GEMM: h[N,256] = x[N,64] @ W[64,256] ----------
__global__ void gemm_64_256(const float* __restrict__ x, const float* __restrict__ W,
                            float* __restrict__ h, int N) {
    __shared__ float Wl[64 * 256];
    __shared__ float xl[2][64];
    for (int i = threadIdx.x; i < 64 * 256; i += 256) Wl[i] = W[i];
    __syncthreads();
    for (long long base = (long long)blockIdx.x * 2; base < N; base += (long long)gridDim.x * 2) {
        for (int i = threadIdx.x; i < 128; i += 256) {
            long long node = base + (i >> 6);
            xl[i >> 6][i & 63] = (node < N) ? x[node * 64 + (i & 63)] : 0.f;
        }
        __syncthreads();
        #pragma unroll
        for (int j = 0; j < 2; ++j) {
            long long node = base + j;
            if (node < N) {
                float acc = 0.f;
                #pragma unroll 8
                for (int k = 0; k < 64; ++k) acc += xl[j][k] * Wl[k * 256 + threadIdx.x];
                h[node * 256 + threadIdx.x] = acc;
            }
        }
        __syncthreads();
    }
}

// ---------- GEMM: h[N,64] = x[N,256] @ W[256,64] ----------
__global__ void gemm_256_64(const float* __restrict__ x, const float* __restrict__ W,
                            float* __restrict__ h, int N) {
    __shared__ float Wl[256 * 64];
    __shared__ float xl[4][256];
    for (int i = threadIdx.x; i < 256 * 64; i += 256) Wl[i] = W[i];
    __syncthreads();
    int c = threadIdx.x & 63;
    int nl = threadIdx.x >> 6;
    for (long long base = (long long)blockIdx.x * 4; base < N; base += (long long)gridDim.x * 4) {
        for (int i = threadIdx.x; i < 4 * 256; i += 256) {
            long long node = base + (i >> 8);
            xl[i >> 8][i & 255] = (node < N) ? x[node * 256 + (i & 255)] : 0.f;
        }
        __syncthreads();
        long long node = base + nl;
        if (node < N) {
            float acc = 0.f;
            #pragma unroll 8
            for (int k = 0; k < 256; ++k) acc += xl[nl][k] * Wl[k * 64 + c];
            h[node * 64 + c] = acc;
        }
        __syncthreads();
    }
}

// ---------- per-node attention scores: a_s/a_d[N,H] ----------
template <int H>
__global__ void attn_scores(const float* __restrict__ h, const float* __restrict__ att_s,
                            const float* __restrict__ att_d, float* __restrict__ a_s,
                            float* __restrict__ a_d, int N) {
    long long wid = ((long long)blockIdx.x * blockDim.x + threadIdx.x) >> 6;
    int lane = threadIdx.x & 63;
    long long total = (long long)N * H;
    if (wid >= total) return;
    int head = (int)(wid % H);
    long long node = wid / H;
    float v = h[node * (H * 64) + head * 64 + lane];
    float vs = v * att_s[head * 64 + lane];
    float vd = v * att_d[head * 64 + lane];
    #pragma unroll
    for (int off = 32; off; off >>= 1) {
        vs += __shfl_down(vs, off);
        vd += __shfl_down(vd, off);
    }
    if (lane == 0) { a_s[node * H + head] = vs; a_d[node * H + head] = vd; }
}

__global__ void fill_u32(unsigned* __restrict__ p, unsigned val, long long n) {
    long long i = (long long)blockIdx.x * blockDim.x + threadIdx.x;
    if (i < n) p[i] = val;
}

// ---------- edge pass 1: per-dst max ----------
template <int H>
__global__ void edge_max(const int* __restrict__ src, const int* __restrict__ dst,
                         const float* __restrict__ a_s, const float* __restrict__ a_d,
                         unsigned* __restrict__ mkey, int E, int ET) {
    int e = blockIdx.x * blockDim.x + threadIdx.x;
    if (e >= ET) return;
    int s = (e < E) ? src[e] : (e - E);
    int d = (e < E) ? dst[e] : (e - E);
    #pragma unroll
    for (int hh = 0; hh < H; ++hh) {
        float el = lrelu(a_s[(long long)s * H + hh] + a_d[(long long)d * H + hh]);
        atomicMax(&mkey[(long long)d * H + hh], fkey(el));
    }
}

// ---------- edge pass 2: per-dst sum of exp ----------
template <int H>
__global__ void edge_denom(const int* __restrict__ src, const int* __restrict__ dst,
                           const float* __restrict__ a_s, const float* __restrict__ a_d,
                           const unsigned* __restrict__ mkey, float* __restrict__ den,
                           int E, int ET) {
    int e = blockIdx.x * blockDim.x + threadIdx.x;
    if (e >= ET) return;
    int s = (e < E) ? src[e] : (e - E);
    int d = (e < E) ? dst[e] : (e - E);
    #pragma unroll
    for (int hh = 0; hh < H; ++hh) {
        float el = lrelu(a_s[(long long)s * H + hh] + a_d[(long long)d * H + hh]);
        float m = funkey(mkey[(long long)d * H + hh]);
        atomAddF(&den[(long long)d * H + hh], expf(el - m));
    }
}

// ---------- edge pass 3: out[dst] += alpha * h[src] (one wave per edge) ----------
template <int H>
__global__ void edge_aggregate(const int* __restrict__ src, const int* __restrict__ dst,
                               const float* __restrict__ a_s, const float* __restrict__ a_d,
                               const unsigned* __restrict__ mkey, const float* __restrict__ den,
                               const float* __restrict__ h, float* __restrict__ out,
                               int E, int ET) {
    long long wid = ((long long)blockIdx.x * blockDim.x + threadIdx.x) >> 6;
    int lane = threadIdx.x & 63;
    if (wid >= ET) return;
    int e = (int)wid;
    int s = (e < E) ? src[e] : (e - E);
    int d = (e < E) ? dst[e] : (e - E);
    #pragma unroll
    for (int hh = 0; hh < H; ++hh) {
        float el = lrelu(a_s[(long long)s * H + hh] + a_d[(long long)d * H + hh]);
        float m = funkey(mkey[(long long)d * H + hh]);
        float alpha = expf(el - m) / (den[(long long)d * H + hh] + 1e-16f);
        float v = h[(long long)s * (H * 64) + hh * 64 + lane];
        atomAddF(&out[(long long)d * (H * 64) + hh * 64 + lane], alpha * v);
    }
}

// ---------- bias + relu ----------
__global__ void bias_relu(float* __restrict__ x, const float* __restrict__ b,
                          long long total, int colmask) {
    long long i = (long long)blockIdx.x * blockDim.x + threadIdx.x;
    if (i < total) {
        float v = x[i] + b[i & colmask];
        x[i] = v > 0.f ? v : 0.f;
    }
}

// ---------- column sum over nodes ----------
__global__ void colsum_kernel(const float* __restrict__ x, float* __restrict__ g, int N) {
    __shared__ float part[4][64];
    int c = threadIdx.x & 63;
    int r = threadIdx.x >> 6;
    float acc = 0.f;
    for (long long n = (long long)blockIdx.x * 4 + r; n < N; n += (long long)gridDim.x * 4)
        acc += x[n * 64 + c];
    part[r][c] = acc;
    __syncthreads();
    if (r == 0) {
        float v = part[0][c] + part[1][c] + part[2][c] + part[3][c];
        atomAddF(&g[c], v);
    }
}

__global__ void final_kernel(const float* __restrict__ g, const float* __restrict__ Wv,
                             const float* __restrict__ bv, float* __restrict__ out, int N) {
    int lane = threadIdx.x;
    float v = (g[lane] / (float)N) * Wv[lane];
    #pragma unroll
    for (int off = 32; off; off >>= 1) v += __shfl_down(v, off);
    if (lane == 0) out[0] = v + bv[0];
}

extern "C" void kernel_launch(void* const* d_in, const int* in_sizes, int n_in,
                              void* d_out, int out_size, void* d_ws, size_t ws_size,
                              hipStream_t stream) {
    const float* nf   = (const float*)d_in[0];
    const float* act  = (const float*)d_in[1];
    const int*   ei   = (const int*)d_in[2];
    const float* Wemb = (const float*)d_in[3];
    const float* bemb = (const float*)d_in[4];
    const float* W1   = (const float*)d_in[5];
    const float* as1  = (const float*)d_in[6];
    const float* ad1  = (const float*)d_in[7];
    const float* b1   = (const float*)d_in[8];
    const float* W2   = (const float*)d_in[9];
    const float* as2  = (const float*)d_in[10];
    const float* ad2  = (const float*)d_in[11];
    const float* b2   = (const float*)d_in[12];
    const float* Wv   = (const float*)d_in[13];
    const float* bv   = (const float*)d_in[14];
    float* out = (float*)d_out;

    const int N = in_sizes[0] / FEAT;
    const int E = in_sizes[2] / 2;
    const int ET = E + N;
    const int* srcp = ei;
    const int* dstp = ei + E;

    // workspace layout (floats); total ~ N*(64+512+16)+64 floats ~ 118 MB
    float* ws = (float*)d_ws;
    float* x0   = ws;                          // N*64
    float* h1   = x0 + (size_t)N * 64;         // N*256
    float* out1 = h1 + (size_t)N * 256;        // N*256
    float* h2   = h1;                          // reuse (h1 dead after GAT1 aggregate)
    float* out2 = h1 + (size_t)N * 64;         // second chunk of h1 buffer
    float* a_s  = out1 + (size_t)N * 256;      // N*4
    float* a_d  = a_s + (size_t)N * 4;         // N*4
    float* den  = a_d + (size_t)N * 4;         // N*4
    unsigned* mkey = (unsigned*)(den + (size_t)N * 4); // N*4
    float* g    = (float*)(mkey + (size_t)N * 4);      // 64

    (void)ws_size; (void)n_in; (void)out_size;
    const unsigned NEG_INF_KEY = 0x007FFFFFu;  // fkey(-inf)

    // ---- embedding ----
    emb_kernel<<<1024, 256, 0, stream>>>(nf, act, Wemb, bemb, x0, N);

    // ---- GAT layer 1 (H=4) ----
    gemm_64_256<<<2048, 256, 0, stream>>>(x0, W1, h1, N);
    {
        long long thr = (long long)N * 4 * 64;
        attn_scores<4><<<(int)((thr + 255) / 256), 256, 0, stream>>>(h1, as1, ad1, a_s, a_d, N);
    }
    hipMemsetAsync(den, 0, (size_t)N * 4 * sizeof(float), stream);
    fill_u32<<<(int)(((long long)N * 4 + 255) / 256), 256, 0, stream>>>(mkey, NEG_INF_KEY, (long long)N * 4);
    edge_max<4><<<(ET + 255) / 256, 256, 0, stream>>>(srcp, dstp, a_s, a_d, mkey, E, ET);
    edge_denom<4><<<(ET + 255) / 256, 256, 0, stream>>>(srcp, dstp, a_s, a_d, mkey, den, E, ET);
    hipMemsetAsync(out1, 0, (size_t)N * 256 * sizeof(float), stream);
    {
        long long thr = (long long)ET * 64;
        edge_aggregate<4><<<(int)((thr + 255) / 256), 256, 0, stream>>>(
            srcp, dstp, a_s, a_d, mkey, den, h1, out1, E, ET);
    }
    bias_relu<<<(int)(((long long)N * 256 + 255) / 256), 256, 0, stream>>>(out1, b1, (long long)N * 256, 255);

    // ---- GAT layer 2 (H=1) ----
    gemm_256_64<<<2048, 256, 0, stream>>>(out1, W2, h2, N);
    {
        long long thr = (long long)N * 64;
        attn_scores<1><<<(int)((thr + 255) / 256), 256, 0, stream>>>(h2, as2, ad2, a_s, a_d, N);
    }
    hipMemsetAsync(den, 0, (size_t)N * sizeof(float), stream);
    fill_u32<<<(int)(((long long)N + 255) / 256), 256, 0, stream>>>(mkey, NEG_INF_KEY, (long long)N);
    edge_max<1><<<(ET + 255) / 256, 256, 0, stream>>>(srcp, dstp, a_s, a_d, mkey, E, ET);
    edge_denom<1><<<(ET + 255) / 256, 256, 0, stream>>>(srcp, dstp, a_s, a_d, mkey, den, E, ET);
    hipMemsetAsync(out2, 0, (size_t)N * 64 * sizeof(float), stream);
    {
        long long thr = (long long)ET * 64;
        edge_aggregate<1><<<(int)((thr + 255) / 256), 256, 0, stream>>>(
            srcp, dstp, a_s, a_d, mkey, den, h2, out2, E, ET);
    }
    bias_relu<<<(int)(((long long)N * 64 + 255) / 256), 256, 0, stream>>>(out2, b2, (long long)N * 64, 63);

    // ---- readout ----
    hipMemsetAsync(g, 0, 64 * sizeof(float), stream);
    colsum_kernel<<<512, 256, 0, stream>>>(out2, g, N);
    final_kernel<<<1, 64, 0, stream>>>(g, Wv, bv, out, N);
}

// Round 2
// 765.088 us; speedup vs baseline: 2.1074x; 2.1074x over previous
//
#include <hip/hip_runtime.h>
#include <hip/hip_bf16.h>
#include <math.h>

#define FEAT 96
#define ACTF 32
#define HID 64

__device__ __forceinline__ float lrelu(float x) { return x >= 0.f ? x : 0.2f * x; }
__device__ __forceinline__ void atomAddF(float* p, float v) {
    __hip_atomic_fetch_add(p, v, __ATOMIC_RELAXED, __HIP_MEMORY_SCOPE_AGENT);
}

// ---------- embedding: x0[N,64] = [nf|act] @ Wemb[128,64] + bemb ----------
__global__ void emb_kernel(const float* __restrict__ nf, const float* __restrict__ act,
                           const float* __restrict__ Wemb, const float* __restrict__ bemb,
                           float* __restrict__ x0, int N) {
    __shared__ float Wl[128 * 64];
    __shared__ float xl[4][128];
    for (int i = threadIdx.x; i < 128 * 64; i += 256) Wl[i] = Wemb[i];
    __syncthreads();
    int c = threadIdx.x & 63;
    int nl = threadIdx.x >> 6;
    for (long long base = (long long)blockIdx.x * 4; base < N; base += (long long)gridDim.x * 4) {
        for (int i = threadIdx.x; i < 4 * 128; i += 256) {
            long long node = base + (i >> 7);
            int k = i & 127;
            float v = 0.f;
            if (node < N) v = (k < FEAT) ? nf[node * FEAT + k] : act[node * ACTF + (k - FEAT)];
            xl[i >> 7][k] = v;
        }
        __syncthreads();
        long long node = base + nl;
        if (node < N) {
            float acc = bemb[c];
            #pragma unroll 8
            for (int k = 0; k < 128; ++k) acc += xl[nl][k] * Wl[k * 64 + c];
            x0[node * 64 + c] = acc;
        }
        __syncthreads();
    }
}

// ---------- GEMM + fused attn scores: h[N,256] = x[N,64] @ W1, a_s/a_d[N,4] ----------
__global__ void gemm1_scores(const float* __restrict__ x, const float* __restrict__ W,
                             const float* __restrict__ att_s, const float* __restrict__ att_d,
                             float* __restrict__ h, float* __restrict__ a_s,
                             float* __restrict__ a_d, int N) {
    __shared__ float Wl[64 * 256];
    __shared__ float xl[2][64];
    for (int i = threadIdx.x; i < 64 * 256; i += 256) Wl[i] = W[i];
    __syncthreads();
    int t = threadIdx.x;
    int head = t >> 6;
    int lane = t & 63;
    float asw = att_s[t];   // att_s[head*64 + ch] == att_s[t]
    float adw = att_d[t];
    for (long long base = (long long)blockIdx.x * 2; base < N; base += (long long)gridDim.x * 2) {
        for (int i = t; i < 128; i += 256) {
            long long node = base + (i >> 6);
            xl[i >> 6][i & 63] = (node < N) ? x[node * 64 + (i & 63)] : 0.f;
        }
        __syncthreads();
        #pragma unroll
        for (int j = 0; j < 2; ++j) {
            long long node = base + j;
            if (node < N) {
                float acc = 0.f;
                #pragma unroll 8
                for (int k = 0; k < 64; ++k) acc += xl[j][k] * Wl[k * 256 + t];
                h[node * 256 + t] = acc;
                float vs = acc * asw, vd = acc * adw;
                #pragma unroll
                for (int o = 32; o; o >>= 1) {
                    vs += __shfl_down(vs, o);
                    vd += __shfl_down(vd, o);
                }
                if (lane == 0) {
                    a_s[node * 4 + head] = vs;
                    a_d[node * 4 + head] = vd;
                }
            }
        }
        __syncthreads();
    }
}

// ---------- GEMM + fused attn scores (H=1): h[N,64] = x[N,256] @ W2 ----------
__global__ void gemm2_scores(const float* __restrict__ x, const float* __restrict__ W,
                             const float* __restrict__ att_s, const float* __restrict__ att_d,
                             float* __restrict__ h, float* __restrict__ a_s,
                             float* __restrict__ a_d, int N) {
    __shared__ float Wl[256 * 64];
    __shared__ float xl[4][256];
    for (int i = threadIdx.x; i < 256 * 64; i += 256) Wl[i] = W[i];
    __syncthreads();
    int c = threadIdx.x & 63;
    int nl = threadIdx.x >> 6;
    float asw = att_s[c], adw = att_d[c];
    for (long long base = (long long)blockIdx.x * 4; base < N; base += (long long)gridDim.x * 4) {
        for (int i = threadIdx.x; i < 4 * 256; i += 256) {
            long long node = base + (i >> 8);
            xl[i >> 8][i & 255] = (node < N) ? x[node * 256 + (i & 255)] : 0.f;
        }
        __syncthreads();
        long long node = base + nl;
        if (node < N) {
            float acc = 0.f;
            #pragma unroll 8
            for (int k = 0; k < 256; ++k) acc += xl[nl][k] * Wl[k * 64 + c];
            h[node * 64 + c] = acc;
            float vs = acc * asw, vd = acc * adw;
            #pragma unroll
            for (int o = 32; o; o >>= 1) {
                vs += __shfl_down(vs, o);
                vd += __shfl_down(vd, o);
            }
            if (c == 0) { a_s[node] = vs; a_d[node] = vd; }
        }
        __syncthreads();
    }
}

// ---------- CSR build ----------
__global__ void hist_kernel(const int* __restrict__ dst, int* __restrict__ cnt, int E, int ET) {
    int e = blockIdx.x * blockDim.x + threadIdx.x;
    if (e >= ET) return;
    int d = (e < E) ? dst[e] : (e - E);
    atomicAdd(&cnt[d], 1);
}

__global__ void scan_kernel(const int* __restrict__ cnt, int* __restrict__ off, int n) {
    __shared__ int part[1024];
    int tid = threadIdx.x;
    int chunk = (n + 1023) >> 10;
    int lo = tid * chunk;
    int hi = lo + chunk; if (hi > n) hi = n; if (lo > n) lo = n;
    int s = 0;
    for (int i = lo; i < hi; ++i) s += cnt[i];
    part[tid] = s;
    __syncthreads();
    #pragma unroll
    for (int d = 1; d < 1024; d <<= 1) {
        int v = (tid >= d) ? part[tid - d] : 0;
        __syncthreads();
        part[tid] += v;
        __syncthreads();
    }
    int run = (tid == 0) ? 0 : part[tid - 1];
    for (int i = lo; i < hi; ++i) { off[i] = run; run += cnt[i]; }
    if (tid == 1023) off[n] = part[1023];
}

__global__ void scatter_kernel(const int* __restrict__ src, const int* __restrict__ dst,
                               const int* __restrict__ off, int* __restrict__ cur,
                               int* __restrict__ perm, int E, int ET) {
    int e = blockIdx.x * blockDim.x + threadIdx.x;
    if (e >= ET) return;
    int s = (e < E) ? src[e] : (e - E);
    int d = (e < E) ? dst[e] : (e - E);
    int r = atomicAdd(&cur[d], 1);
    perm[off[d] + r] = s;
}

// ---------- fused GAT aggregate (H=4): one block of 256 per dst ----------
// thread t -> head t>>6, channel t&63. Online softmax in registers, no atomics.
__global__ void fused_gat4(const int* __restrict__ off, const int* __restrict__ perm,
                           const float* __restrict__ a_s, const float* __restrict__ a_d,
                           const float* __restrict__ h, const float* __restrict__ bias,
                           float* __restrict__ outp, int N) {
    int d = blockIdx.x;
    if (d >= N) return;
    int t = threadIdx.x;
    int hh = t >> 6;
    float add = a_d[(long long)d * 4 + hh];
    int lo = off[d], hi = off[d + 1];
    float m = -3.4e38f, den = 0.f, acc = 0.f;
    for (int e = lo; e < hi; ++e) {
        int s = perm[e];
        float el = lrelu(a_s[(long long)s * 4 + hh] + add);
        float mn = fmaxf(m, el);
        float scale = __expf(m - mn);
        float p = __expf(el - mn);
        den = den * scale + p;
        acc = acc * scale + p * h[(long long)s * 256 + t];
        m = mn;
    }
    float v = acc / (den + 1e-16f) + bias[t];
    outp[(long long)d * 256 + t] = v > 0.f ? v : 0.f;
}

// ---------- fused GAT aggregate (H=1): one wave per dst, 4 dst per block ----------
__global__ void fused_gat1(const int* __restrict__ off, const int* __restrict__ perm,
                           const float* __restrict__ a_s, const float* __restrict__ a_d,
                           const float* __restrict__ h, const float* __restrict__ bias,
                           float* __restrict__ outp, int N) {
    int d = blockIdx.x * 4 + (threadIdx.x >> 6);
    if (d >= N) return;
    int lane = threadIdx.x & 63;
    float add = a_d[d];
    int lo = off[d], hi = off[d + 1];
    float m = -3.4e38f, den = 0.f, acc = 0.f;
    for (int e = lo; e < hi; ++e) {
        int s = perm[e];
        float el = lrelu(a_s[s] + add);
        float mn = fmaxf(m, el);
        float scale = __expf(m - mn);
        float p = __expf(el - mn);
        den = den * scale + p;
        acc = acc * scale + p * h[(long long)s * 64 + lane];
        m = mn;
    }
    float v = acc / (den + 1e-16f) + bias[lane];
    outp[(long long)d * 64 + lane] = v > 0.f ? v : 0.f;
}

// ---------- column sum over nodes ----------
__global__ void colsum_kernel(const float* __restrict__ x, float* __restrict__ g, int N) {
    __shared__ float part[4][64];
    int c = threadIdx.x & 63;
    int r = threadIdx.x >> 6;
    float acc = 0.f;
    for (long long n = (long long)blockIdx.x * 4 + r; n < N; n += (long long)gridDim.x * 4)
        acc += x[n * 64 + c];
    part[r][c] = acc;
    __syncthreads();
    if (r == 0) {
        float v = part[0][c] + part[1][c] + part[2][c] + part[3][c];
        atomAddF(&g[c], v);
    }
}

__global__ void final_kernel(const float* __restrict__ g, const float* __restrict__ Wv,
                             const float* __restrict__ bv, float* __restrict__ out, int N) {
    int lane = threadIdx.x;
    float v = (g[lane] / (float)N) * Wv[lane];
    #pragma unroll
    for (int off = 32; off; off >>= 1) v += __shfl_down(v, off);
    if (lane == 0) out[0] = v + bv[0];
}

extern "C" void kernel_launch(void* const* d_in, const int* in_sizes, int n_in,
                              void* d_out, int out_size, void* d_ws, size_t ws_size,
                              hipStream_t stream) {
    const float* nf   = (const float*)d_in[0];
    const float* act  = (const float*)d_in[1];
    const int*   ei   = (const int*)d_in[2];
    const float* Wemb = (const float*)d_in[3];
    const float* bemb = (const float*)d_in[4];
    const float* W1   = (const float*)d_in[5];
    const float* as1  = (const float*)d_in[6];
    const float* ad1  = (const float*)d_in[7];
    const float* b1   = (const float*)d_in[8];
    const float* W2   = (const float*)d_in[9];
    const float* as2  = (const float*)d_in[10];
    const float* ad2  = (const float*)d_in[11];
    const float* b2   = (const float*)d_in[12];
    const float* Wv   = (const float*)d_in[13];
    const float* bv   = (const float*)d_in[14];
    float* out = (float*)d_out;

    const int N = in_sizes[0] / FEAT;
    const int E = in_sizes[2] / 2;
    const int ET = E + N;
    const int* srcp = ei;
    const int* dstp = ei + E;

    // ---- workspace layout (floats) ----
    // x0 region is reused for CSR ints once gemm1 has consumed x0.
    float* ws = (float*)d_ws;
    float* x0   = ws;                          // N*64 floats (12.8 MB)
    float* h1   = x0 + (size_t)N * 64;         // N*256
    float* out1 = h1 + (size_t)N * 256;        // N*256
    float* a_s  = out1 + (size_t)N * 256;      // N*4
    float* a_d  = a_s + (size_t)N * 4;         // N*4
    float* g    = a_d + (size_t)N * 4;         // 64
    // layer-2 reuse
    float* h2   = h1;                          // N*64
    float* out2 = h1 + (size_t)N * 64;         // N*64
    // CSR carved from x0 region (3N+1+ET ints = ~4 MB < 12.8 MB)
    int* cnt  = (int*)x0;                      // N
    int* off  = cnt + N;                       // N+1
    int* cur  = off + N + 1;                   // N
    int* perm = cur + N;                       // ET

    (void)ws_size; (void)n_in; (void)out_size;

    // ---- embedding ----
    emb_kernel<<<1024, 256, 0, stream>>>(nf, act, Wemb, bemb, x0, N);

    // ---- GAT layer 1: GEMM + scores ----
    gemm1_scores<<<2048, 256, 0, stream>>>(x0, W1, as1, ad1, h1, a_s, a_d, N);

    // ---- CSR build (x0 now dead) ----
    hipMemsetAsync(cnt, 0, (size_t)N * sizeof(int), stream);
    hipMemsetAsync(cur, 0, (size_t)N * sizeof(int), stream);
    hist_kernel<<<(ET + 255) / 256, 256, 0, stream>>>(dstp, cnt, E, ET);
    scan_kernel<<<1, 1024, 0, stream>>>(cnt, off, N);
    scatter_kernel<<<(ET + 255) / 256, 256, 0, stream>>>(srcp, dstp, off, cur, perm, E, ET);

    // ---- GAT layer 1: fused max/softmax/aggregate/bias/relu ----
    fused_gat4<<<N, 256, 0, stream>>>(off, perm, a_s, a_d, h1, b1, out1, N);

    // ---- GAT layer 2 ----
    gemm2_scores<<<2048, 256, 0, stream>>>(out1, W2, as2, ad2, h2, a_s, a_d, N);
    fused_gat1<<<(N + 3) / 4, 256, 0, stream>>>(off, perm, a_s, a_d, h2, b2, out2, N);

    // ---- readout ----
    hipMemsetAsync(g, 0, 64 * sizeof(float), stream);
    colsum_kernel<<<512, 256, 0, stream>>>(out2, g, N);
    final_kernel<<<1, 64, 0, stream>>>(g, Wv, bv, out, N);
}

// Round 3
// 603.320 us; speedup vs baseline: 2.6724x; 1.2681x over previous
//
#include <hip/hip_runtime.h>
#include <hip/hip_bf16.h>
#include <math.h>

#define FEAT 96
#define ACTF 32

__device__ __forceinline__ float lrelu(float x) { return x >= 0.f ? x : 0.2f * x; }
__device__ __forceinline__ void atomAddF(float* p, float v) {
    __hip_atomic_fetch_add(p, v, __ATOMIC_RELAXED, __HIP_MEMORY_SCOPE_AGENT);
}

// ---------- embedding: x0[N,64] = [nf|act] @ Wemb[128,64] + bemb ----------
__global__ void emb_kernel(const float* __restrict__ nf, const float* __restrict__ act,
                           const float* __restrict__ Wemb, const float* __restrict__ bemb,
                           float* __restrict__ x0, int N) {
    __shared__ float Wl[128 * 64];
    __shared__ float xl[4][128];
    for (int i = threadIdx.x; i < 128 * 64; i += 256) Wl[i] = Wemb[i];
    __syncthreads();
    int c = threadIdx.x & 63;
    int nl = threadIdx.x >> 6;
    for (long long base = (long long)blockIdx.x * 4; base < N; base += (long long)gridDim.x * 4) {
        for (int i = threadIdx.x; i < 4 * 128; i += 256) {
            long long node = base + (i >> 7);
            int k = i & 127;
            float v = 0.f;
            if (node < N) v = (k < FEAT) ? nf[node * FEAT + k] : act[node * ACTF + (k - FEAT)];
            xl[i >> 7][k] = v;
        }
        __syncthreads();
        long long node = base + nl;
        if (node < N) {
            float acc = bemb[c];
            #pragma unroll 8
            for (int k = 0; k < 128; ++k) acc += xl[nl][k] * Wl[k * 64 + c];
            x0[node * 64 + c] = acc;
        }
        __syncthreads();
    }
}

// ---------- GEMM1 + scores: h1b[N,256](bf16) = x[N,64]@W1; a_s/a_d[N,4] ----------
// Thread t owns output channel t; W column in 64 VGPRs; x row is wave-uniform.
__global__ __launch_bounds__(256) void gemm1_scores(
    const float* __restrict__ x, const float* __restrict__ W,
    const float* __restrict__ att_s, const float* __restrict__ att_d,
    __hip_bfloat16* __restrict__ h1b, float* __restrict__ a_s,
    float* __restrict__ a_d, int N) {
    int t = threadIdx.x;
    int head = t >> 6, lane = t & 63;
    float wk[64];
    #pragma unroll
    for (int k = 0; k < 64; ++k) wk[k] = W[k * 256 + t];
    float asw = att_s[t], adw = att_d[t];
    for (int node = blockIdx.x; node < N; node += gridDim.x) {
        const float4* xr = (const float4*)(x + (size_t)node * 64);
        float a0 = 0.f, a1 = 0.f, a2 = 0.f, a3 = 0.f;
        #pragma unroll
        for (int kq = 0; kq < 16; ++kq) {
            float4 xv = xr[kq];
            a0 = fmaf(xv.x, wk[4 * kq + 0], a0);
            a1 = fmaf(xv.y, wk[4 * kq + 1], a1);
            a2 = fmaf(xv.z, wk[4 * kq + 2], a2);
            a3 = fmaf(xv.w, wk[4 * kq + 3], a3);
        }
        float acc = (a0 + a1) + (a2 + a3);
        h1b[(size_t)node * 256 + t] = __float2bfloat16(acc);
        float vs = acc * asw, vd = acc * adw;
        #pragma unroll
        for (int o = 32; o; o >>= 1) {
            vs += __shfl_down(vs, o);
            vd += __shfl_down(vd, o);
        }
        if (lane == 0) {
            a_s[(size_t)node * 4 + head] = vs;
            a_d[(size_t)node * 4 + head] = vd;
        }
    }
}

// ---------- GEMM2 + scores: h2[N,64] = x[N,256]@W2; a_s/a_d[N] ----------
// Wave w handles k-quarter w; thread lane owns channel; cross-wave LDS reduce.
__global__ __launch_bounds__(256) void gemm2_scores(
    const float* __restrict__ x, const float* __restrict__ W,
    const float* __restrict__ att_s, const float* __restrict__ att_d,
    float* __restrict__ h2, float* __restrict__ a_s, float* __restrict__ a_d, int N) {
    int t = threadIdx.x;
    int w = t >> 6, c = t & 63;
    float wk[64];
    #pragma unroll
    for (int k = 0; k < 64; ++k) wk[k] = W[(size_t)(w * 64 + k) * 64 + c];
    __shared__ float part[3][4][64];
    float asw = att_s[c], adw = att_d[c];
    for (int base = blockIdx.x * 4; base < N; base += gridDim.x * 4) {
        float acc0 = 0.f, acc1 = 0.f, acc2 = 0.f, acc3 = 0.f;
        #pragma unroll
        for (int j = 0; j < 4; ++j) {
            int node = base + j; if (node >= N) node = N - 1;   // clamp, store guarded later
            const float4* xr = (const float4*)(x + (size_t)node * 256 + w * 64);
            float b0 = 0.f, b1 = 0.f, b2 = 0.f, b3 = 0.f;
            #pragma unroll
            for (int kq = 0; kq < 16; ++kq) {
                float4 xv = xr[kq];
                b0 = fmaf(xv.x, wk[4 * kq + 0], b0);
                b1 = fmaf(xv.y, wk[4 * kq + 1], b1);
                b2 = fmaf(xv.z, wk[4 * kq + 2], b2);
                b3 = fmaf(xv.w, wk[4 * kq + 3], b3);
            }
            float s = (b0 + b1) + (b2 + b3);
            if (j == 0) acc0 = s; else if (j == 1) acc1 = s; else if (j == 2) acc2 = s; else acc3 = s;
        }
        if (w) {
            part[w - 1][0][c] = acc0; part[w - 1][1][c] = acc1;
            part[w - 1][2][c] = acc2; part[w - 1][3][c] = acc3;
        }
        __syncthreads();
        if (w == 0) {
            float accs[4] = {acc0, acc1, acc2, acc3};
            #pragma unroll
            for (int j = 0; j < 4; ++j) {
                float s = accs[j] + part[0][j][c] + part[1][j][c] + part[2][j][c];
                float vs = s * asw, vd = s * adw;
                #pragma unroll
                for (int o = 32; o; o >>= 1) {
                    vs += __shfl_down(vs, o);
                    vd += __shfl_down(vd, o);
                }
                if (base + j < N) {
                    h2[(size_t)(base + j) * 64 + c] = s;
                    if (c == 0) { a_s[base + j] = vs; a_d[base + j] = vd; }
                }
            }
        }
        __syncthreads();
    }
}

// ---------- CSR build ----------
__global__ void hist_kernel(const int* __restrict__ dst, int* __restrict__ cnt, int E, int ET) {
    int e = blockIdx.x * blockDim.x + threadIdx.x;
    if (e >= ET) return;
    int d = (e < E) ? dst[e] : (e - E);
    atomicAdd(&cnt[d], 1);
}

__global__ void scan_kernel(const int* __restrict__ cnt, int* __restrict__ off, int n) {
    __shared__ int part[1024];
    int tid = threadIdx.x;
    int chunk = (n + 1023) >> 10;
    int lo = tid * chunk;
    int hi = lo + chunk; if (hi > n) hi = n; if (lo > n) lo = n;
    int s = 0;
    for (int i = lo; i < hi; ++i) s += cnt[i];
    part[tid] = s;
    __syncthreads();
    #pragma unroll
    for (int d = 1; d < 1024; d <<= 1) {
        int v = (tid >= d) ? part[tid - d] : 0;
        __syncthreads();
        part[tid] += v;
        __syncthreads();
    }
    int run = (tid == 0) ? 0 : part[tid - 1];
    for (int i = lo; i < hi; ++i) { off[i] = run; run += cnt[i]; }
    if (tid == 1023) off[n] = part[1023];
}

__global__ void scatter_kernel(const int* __restrict__ src, const int* __restrict__ dst,
                               const int* __restrict__ off, int* __restrict__ cur,
                               int* __restrict__ perm, int E, int ET) {
    int e = blockIdx.x * blockDim.x + threadIdx.x;
    if (e >= ET) return;
    int s = (e < E) ? src[e] : (e - E);
    int d = (e < E) ? dst[e] : (e - E);
    int r = atomicAdd(&cur[d], 1);
    perm[off[d] + r] = s;
}

// ---------- fused GAT layer 1 (H=4): block per dst; wave per head ----------
// Phase A: wave-parallel (m, den) stats. Phase B: gather h1b (bf16), 4x unrolled.
__global__ __launch_bounds__(256) void fused_gat4(
    const int* __restrict__ off, const int* __restrict__ perm,
    const float* __restrict__ a_s, const float* __restrict__ a_d,
    const __hip_bfloat16* __restrict__ h1b, const float* __restrict__ bias,
    float* __restrict__ out1, int N) {
    int d = blockIdx.x;
    if (d >= N) return;
    int t = threadIdx.x, hh = t >> 6, lane = t & 63;
    int lo = off[d], hi = off[d + 1];
    float add = a_d[(size_t)d * 4 + hh];
    float lm = -3.4e38f, lden = 0.f;
    for (int e = lo + lane; e < hi; e += 64) {
        int s = perm[e];
        float el = lrelu(a_s[(size_t)s * 4 + hh] + add);
        float mn = fmaxf(lm, el);
        lden = lden * __expf(lm - mn) + __expf(el - mn);
        lm = mn;
    }
    #pragma unroll
    for (int o = 32; o; o >>= 1) {
        float om = __shfl_xor(lm, o);
        float od = __shfl_xor(lden, o);
        float mn = fmaxf(lm, om);
        lden = lden * __expf(lm - mn) + od * __expf(om - mn);
        lm = mn;
    }
    float r = 1.f / (lden + 1e-16f);
    float acc0 = 0.f, acc1 = 0.f, acc2 = 0.f, acc3 = 0.f;
    int e = lo;
    for (; e + 4 <= hi; e += 4) {
        int s0 = perm[e], s1 = perm[e + 1], s2 = perm[e + 2], s3 = perm[e + 3];
        float el0 = lrelu(a_s[(size_t)s0 * 4 + hh] + add);
        float el1 = lrelu(a_s[(size_t)s1 * 4 + hh] + add);
        float el2 = lrelu(a_s[(size_t)s2 * 4 + hh] + add);
        float el3 = lrelu(a_s[(size_t)s3 * 4 + hh] + add);
        float v0 = __bfloat162float(h1b[(size_t)s0 * 256 + t]);
        float v1 = __bfloat162float(h1b[(size_t)s1 * 256 + t]);
        float v2 = __bfloat162float(h1b[(size_t)s2 * 256 + t]);
        float v3 = __bfloat162float(h1b[(size_t)s3 * 256 + t]);
        acc0 = fmaf(__expf(el0 - lm) * r, v0, acc0);
        acc1 = fmaf(__expf(el1 - lm) * r, v1, acc1);
        acc2 = fmaf(__expf(el2 - lm) * r, v2, acc2);
        acc3 = fmaf(__expf(el3 - lm) * r, v3, acc3);
    }
    for (; e < hi; ++e) {
        int s = perm[e];
        float el = lrelu(a_s[(size_t)s * 4 + hh] + add);
        float v = __bfloat162float(h1b[(size_t)s * 256 + t]);
        acc0 = fmaf(__expf(el - lm) * r, v, acc0);
    }
    float v = (acc0 + acc1) + (acc2 + acc3) + bias[t];
    out1[(size_t)d * 256 + t] = fmaxf(v, 0.f);
}

// ---------- fused GAT layer 2 (H=1): wave per dst, 4 dst/block ----------
__global__ __launch_bounds__(256) void fused_gat1(
    const int* __restrict__ off, const int* __restrict__ perm,
    const float* __restrict__ a_s, const float* __restrict__ a_d,
    const float* __restrict__ h2, const float* __restrict__ bias,
    float* __restrict__ out2, int N) {
    int d = blockIdx.x * 4 + (threadIdx.x >> 6);
    if (d >= N) return;
    int lane = threadIdx.x & 63;
    int lo = off[d], hi = off[d + 1];
    float add = a_d[d];
    float lm = -3.4e38f, lden = 0.f;
    for (int e = lo + lane; e < hi; e += 64) {
        int s = perm[e];
        float el = lrelu(a_s[s] + add);
        float mn = fmaxf(lm, el);
        lden = lden * __expf(lm - mn) + __expf(el - mn);
        lm = mn;
    }
    #pragma unroll
    for (int o = 32; o; o >>= 1) {
        float om = __shfl_xor(lm, o);
        float od = __shfl_xor(lden, o);
        float mn = fmaxf(lm, om);
        lden = lden * __expf(lm - mn) + od * __expf(om - mn);
        lm = mn;
    }
    float r = 1.f / (lden + 1e-16f);
    float acc0 = 0.f, acc1 = 0.f, acc2 = 0.f, acc3 = 0.f;
    int e = lo;
    for (; e + 4 <= hi; e += 4) {
        int s0 = perm[e], s1 = perm[e + 1], s2 = perm[e + 2], s3 = perm[e + 3];
        float el0 = lrelu(a_s[s0] + add);
        float el1 = lrelu(a_s[s1] + add);
        float el2 = lrelu(a_s[s2] + add);
        float el3 = lrelu(a_s[s3] + add);
        float v0 = h2[(size_t)s0 * 64 + lane];
        float v1 = h2[(size_t)s1 * 64 + lane];
        float v2 = h2[(size_t)s2 * 64 + lane];
        float v3 = h2[(size_t)s3 * 64 + lane];
        acc0 = fmaf(__expf(el0 - lm) * r, v0, acc0);
        acc1 = fmaf(__expf(el1 - lm) * r, v1, acc1);
        acc2 = fmaf(__expf(el2 - lm) * r, v2, acc2);
        acc3 = fmaf(__expf(el3 - lm) * r, v3, acc3);
    }
    for (; e < hi; ++e) {
        int s = perm[e];
        float el = lrelu(a_s[s] + add);
        acc0 = fmaf(__expf(el - lm) * r, h2[(size_t)s * 64 + lane], acc0);
    }
    float v = (acc0 + acc1) + (acc2 + acc3) + bias[lane];
    out2[(size_t)d * 64 + lane] = fmaxf(v, 0.f);
}

// ---------- column sum over nodes ----------
__global__ void colsum_kernel(const float* __restrict__ x, float* __restrict__ g, int N) {
    __shared__ float part[4][64];
    int c = threadIdx.x & 63;
    int r = threadIdx.x >> 6;
    float acc = 0.f;
    for (long long n = (long long)blockIdx.x * 4 + r; n < N; n += (long long)gridDim.x * 4)
        acc += x[n * 64 + c];
    part[r][c] = acc;
    __syncthreads();
    if (r == 0) {
        float v = part[0][c] + part[1][c] + part[2][c] + part[3][c];
        atomAddF(&g[c], v);
    }
}

__global__ void final_kernel(const float* __restrict__ g, const float* __restrict__ Wv,
                             const float* __restrict__ bv, float* __restrict__ out, int N) {
    int lane = threadIdx.x;
    float v = (g[lane] / (float)N) * Wv[lane];
    #pragma unroll
    for (int off = 32; off; off >>= 1) v += __shfl_down(v, off);
    if (lane == 0) out[0] = v + bv[0];
}

extern "C" void kernel_launch(void* const* d_in, const int* in_sizes, int n_in,
                              void* d_out, int out_size, void* d_ws, size_t ws_size,
                              hipStream_t stream) {
    const float* nf   = (const float*)d_in[0];
    const float* act  = (const float*)d_in[1];
    const int*   ei   = (const int*)d_in[2];
    const float* Wemb = (const float*)d_in[3];
    const float* bemb = (const float*)d_in[4];
    const float* W1   = (const float*)d_in[5];
    const float* as1  = (const float*)d_in[6];
    const float* ad1  = (const float*)d_in[7];
    const float* b1   = (const float*)d_in[8];
    const float* W2   = (const float*)d_in[9];
    const float* as2  = (const float*)d_in[10];
    const float* ad2  = (const float*)d_in[11];
    const float* b2   = (const float*)d_in[12];
    const float* Wv   = (const float*)d_in[13];
    const float* bv   = (const float*)d_in[14];
    float* out = (float*)d_out;

    const int N = in_sizes[0] / FEAT;
    const int E = in_sizes[2] / 2;
    const int ET = E + N;
    const int* srcp = ei;
    const int* dstp = ei + E;

    // ---- workspace layout ----
    float* ws = (float*)d_ws;
    float* x0 = ws;                                                 // N*64 f32
    __hip_bfloat16* h1b = (__hip_bfloat16*)(x0 + (size_t)N * 64);   // N*256 bf16
    float* out1 = (float*)(h1b + (size_t)N * 256);                  // N*256 f32
    float* a_s  = out1 + (size_t)N * 256;                           // N*4
    float* a_d  = a_s + (size_t)N * 4;                              // N*4
    float* h2   = a_d + (size_t)N * 4;                              // N*64
    float* out2 = h2 + (size_t)N * 64;                              // N*64
    float* g    = out2 + (size_t)N * 64;                            // 64
    // CSR carved from x0 region (x0 dead after gemm1_scores)
    int* cnt  = (int*)x0;        // N
    int* off  = cnt + N;         // N+1
    int* cur  = off + N + 1;     // N
    int* perm = cur + N;         // ET

    (void)ws_size; (void)n_in; (void)out_size;

    // ---- embedding ----
    emb_kernel<<<1024, 256, 0, stream>>>(nf, act, Wemb, bemb, x0, N);

    // ---- GAT layer 1: GEMM + scores (writes bf16 h1b) ----
    gemm1_scores<<<2048, 256, 0, stream>>>(x0, W1, as1, ad1, h1b, a_s, a_d, N);

    // ---- CSR build (x0 now dead) ----
    hipMemsetAsync(cnt, 0, (size_t)N * sizeof(int), stream);
    hipMemsetAsync(cur, 0, (size_t)N * sizeof(int), stream);
    hist_kernel<<<(ET + 255) / 256, 256, 0, stream>>>(dstp, cnt, E, ET);
    scan_kernel<<<1, 1024, 0, stream>>>(cnt, off, N);
    scatter_kernel<<<(ET + 255) / 256, 256, 0, stream>>>(srcp, dstp, off, cur, perm, E, ET);

    // ---- GAT layer 1: fused stats + softmax + aggregate + bias + relu ----
    fused_gat4<<<N, 256, 0, stream>>>(off, perm, a_s, a_d, h1b, b1, out1, N);

    // ---- GAT layer 2 ----
    gemm2_scores<<<2048, 256, 0, stream>>>(out1, W2, as2, ad2, h2, a_s, a_d, N);
    fused_gat1<<<(N + 3) / 4, 256, 0, stream>>>(off, perm, a_s, a_d, h2, b2, out2, N);

    // ---- readout ----
    hipMemsetAsync(g, 0, 64 * sizeof(float), stream);
    colsum_kernel<<<512, 256, 0, stream>>>(out2, g, N);
    final_kernel<<<1, 64, 0, stream>>>(g, Wv, bv, out, N);
}